// Round 1
// baseline (1249.493 us; speedup 1.0000x reference)
//
#include <hip/hip_runtime.h>
#include <hip/hip_bf16.h>

#define NNODE 2048
#define PTS   128
#define NGRAPH 16

__device__ __forceinline__ int lmap(int m) { return m == 0 ? 0 : (m < 4 ? 1 : (m < 9 ? 2 : 3)); }

__device__ __forceinline__ void sph16(float x, float y, float z, float* Y) {
    Y[0] = 0.28209479177f;
    Y[1] = 0.4886025119f * y; Y[2] = 0.4886025119f * z; Y[3] = 0.4886025119f * x;
    Y[4] = 1.09254843059f * x * y;
    Y[5] = 1.09254843059f * y * z;
    Y[6] = 0.31539156525f * (3.f * z * z - 1.f);
    Y[7] = 1.09254843059f * x * z;
    Y[8] = 0.54627421529f * (x * x - y * y);
    Y[9]  = 0.59004358992f * y * (3.f * x * x - y * y);
    Y[10] = 2.89061144264f * x * y * z;
    Y[11] = 0.45704579946f * y * (5.f * z * z - 1.f);
    Y[12] = 0.37317633259f * z * (5.f * z * z - 3.f);
    Y[13] = 0.45704579946f * x * (5.f * z * z - 1.f);
    Y[14] = 1.44530572132f * z * (x * x - y * y);
    Y[15] = 0.59004358992f * x * (x * x - 3.f * y * y);
}

// ---------------- per-layer node kernel: vpre = h @ Wv[l],  wqk = Wk @ (h0 @ Wq) ----
__global__ __launch_bounds__(256) void k_node_pre(
    const float* __restrict__ h, const float* __restrict__ Wv,
    const float* __restrict__ Wq, const float* __restrict__ Wk,
    float* __restrict__ vpre, float* __restrict__ wqk, int layer)
{
    __shared__ float hs[512];
    __shared__ float Wvs[4096];
    __shared__ float qs[32];
    int n = blockIdx.x, t = threadIdx.x;
    const float* hb = h + n * 512;
    for (int o = t; o < 512; o += 256) hs[o] = hb[o];
    const float* wv = Wv + layer * 4096;
    for (int o = t; o < 4096; o += 256) Wvs[o] = wv[o];
    __syncthreads();
    for (int o = t; o < 512; o += 256) {
        int d = o >> 4, m = o & 15, l = lmap(m);
        float s = 0.f;
        const float* wb = &Wvs[l * 1024 + d];
#pragma unroll
        for (int c = 0; c < 32; c++) s += hs[c * 16 + m] * wb[c * 32];
        vpre[n * 512 + o] = s;
    }
    if (t < 32) {
        float s = 0.f;
        const float* wq = Wq + layer * 1024;
#pragma unroll
        for (int c = 0; c < 32; c++) s += hs[c * 16] * wq[c * 32 + t];
        qs[t] = s;
    }
    __syncthreads();
    if (t < 32) {
        float s = 0.f;
        const float* wk = Wk + layer * 1024;
#pragma unroll
        for (int j = 0; j < 32; j++) s += wk[t * 32 + j] * qs[j];
        wqk[n * 32 + t] = s;
    }
}

// ---------------- per-layer edge kernel: one block per dst node -------------------
__global__ __launch_bounds__(256) void k_edge(
    const float* __restrict__ x, const float* __restrict__ h,
    const float* __restrict__ vpre, const float* __restrict__ wqk,
    const float* __restrict__ w1, const float* __restrict__ b1,
    const float* __restrict__ rW, const float* __restrict__ sW,
    float* __restrict__ agg, int layer)
{
    __shared__ float xs[384];
    __shared__ float w1s[512];
    __shared__ float b1s[32];
    __shared__ float wqks[32];
    __shared__ float rws[4096];
    __shared__ float sws[4096];
    __shared__ float rhs[128 * 33];  // overlaid later as aggred[8][32][16]
    __shared__ float yss[128 * 17];
    __shared__ float alphas[128];
    __shared__ float red[256];
    __shared__ float sh_inv;

    int n = blockIdx.x, t = threadIdx.x;
    int g = n >> 7, b = n & 127;
    int gbase = g << 7;

    for (int o = t; o < 384; o += 256) xs[o] = x[gbase * 3 + o];
    for (int o = t; o < 512; o += 256) w1s[o] = w1[layer * 512 + o];
    if (t < 32) { b1s[t] = b1[layer * 32 + t]; wqks[t] = wqk[n * 32 + t]; }
    for (int o = t; o < 4096; o += 256) { rws[o] = rW[layer * 4096 + o]; sws[o] = sW[layer * 4096 + o]; }
    __syncthreads();

    // phase A: per-edge geometry, rh, logit
    if (t < 128) {
        int a = t;
        float rx = xs[b * 3 + 0] - xs[a * 3 + 0];
        float ry = xs[b * 3 + 1] - xs[a * 3 + 1];
        float rz = xs[b * 3 + 2] - xs[a * 3 + 2];
        float dd = sqrtf(rx * rx + ry * ry + rz * rz + 1e-12f);
        float inv = 1.f / dd;
        float ys[16];
        sph16(rx * inv, ry * inv, rz * inv, ys);
#pragma unroll
        for (int m = 0; m < 16; m++) yss[a * 17 + m] = ys[m];
        float rbf[16];
#pragma unroll
        for (int j = 0; j < 16; j++) {
            float dc = dd - (4.f / 15.f) * j;
            rbf[j] = __expf(-2.f * dc * dc);
        }
        float logit = 0.f;
        for (int d = 0; d < 32; d++) {
            float s = b1s[d];
#pragma unroll
            for (int j = 0; j < 16; j++) s += rbf[j] * w1s[j * 32 + d];
            s = fmaxf(s, 0.f);
            rhs[a * 33 + d] = s;
            logit += s * wqks[d];
        }
        alphas[a] = logit * 0.17677669529663687f;  // 1/sqrt(32)
    }
    __syncthreads();

    // segment softmax over the 127 valid edges
    red[t] = (t < 128 && t != b) ? alphas[t] : -1e30f;
    __syncthreads();
    for (int s = 128; s > 0; s >>= 1) { if (t < s) red[t] = fmaxf(red[t], red[t + s]); __syncthreads(); }
    float mx = red[0];
    __syncthreads();
    float e = (t < 128 && t != b) ? __expf(alphas[t] - mx) : 0.f;
    red[t] = e;
    __syncthreads();
    for (int s = 128; s > 0; s >>= 1) { if (t < s) red[t] += red[t + s]; __syncthreads(); }
    if (t == 0) sh_inv = 1.f / red[0];
    if (t < 128) alphas[t] = e;
    __syncthreads();

    // pass 2: accumulate agg over sources
    int grp = t >> 5, d = t & 31;
    float acc[16];
#pragma unroll
    for (int m = 0; m < 16; m++) acc[m] = 0.f;

    for (int it = 0; it < 16; ++it) {
        int a = grp * 16 + it;
        float w = alphas[a];
        if (w != 0.f) {
            float R[4], S[4];
#pragma unroll
            for (int l = 0; l < 4; l++) {
                float r = 0.f, s2 = 0.f;
                const float* rw = &rws[l * 1024 + d];
                const float* sw = &sws[l * 1024 + d];
                const float* rh = &rhs[a * 33];
#pragma unroll
                for (int j = 0; j < 32; j++) {
                    float rv = rh[j];
                    r  += rv * rw[j * 32];
                    s2 += rv * sw[j * 32];
                }
                R[l] = r; S[l] = s2;
            }
            int nb = (gbase + a) * 512 + d * 16;
            float h0v = h[nb];
            const float4* vp4 = reinterpret_cast<const float4*>(vpre + nb);
            float4 v0 = vp4[0], v1 = vp4[1], v2 = vp4[2], v3 = vp4[3];
            float vp[16] = { v0.x, v0.y, v0.z, v0.w, v1.x, v1.y, v1.z, v1.w,
                             v2.x, v2.y, v2.z, v2.w, v3.x, v3.y, v3.z, v3.w };
            float hb1 = h0v + 1.f;
            float sc0 = S[0] * hb1, sc1 = S[1] * hb1, sc2 = S[2] * hb1, sc3 = S[3] * hb1;
            const float* ysa = &yss[a * 17];
            acc[0] += w * (vp[0] * R[0] + sc0 * ysa[0]);
#pragma unroll
            for (int m = 1; m < 4; m++)  acc[m] += w * (vp[m] * R[1] + sc1 * ysa[m]);
#pragma unroll
            for (int m = 4; m < 9; m++)  acc[m] += w * (vp[m] * R[2] + sc2 * ysa[m]);
#pragma unroll
            for (int m = 9; m < 16; m++) acc[m] += w * (vp[m] * R[3] + sc3 * ysa[m]);
        }
    }
    __syncthreads();
    float* aggred = rhs;  // reuse (rhs reads all done)
#pragma unroll
    for (int m = 0; m < 16; m++) aggred[grp * 512 + d * 16 + m] = acc[m];
    __syncthreads();
    float invs = sh_inv;
    for (int o = t; o < 512; o += 256) {
        float s = 0.f;
#pragma unroll
        for (int g2 = 0; g2 < 8; g2++) s += aggred[g2 * 512 + o];
        agg[n * 512 + o] = s * invs;
    }
}

// ---------------- per-layer node finish: skip + Wo mix, norm-gate -----------------
__global__ __launch_bounds__(256) void k_node_post(
    const float* __restrict__ h, const float* __restrict__ agg,
    const float* __restrict__ Wskip, const float* __restrict__ Wo,
    const float* __restrict__ gw, const float* __restrict__ gb,
    float* __restrict__ hnew, int layer)
{
    __shared__ float hs[512], as[512], wsk[4096], wos[4096], hn[512], scale[128];
    int n = blockIdx.x, t = threadIdx.x;
    for (int o = t; o < 512; o += 256) { hs[o] = h[n * 512 + o]; as[o] = agg[n * 512 + o]; }
    for (int o = t; o < 4096; o += 256) { wsk[o] = Wskip[layer * 4096 + o]; wos[o] = Wo[layer * 4096 + o]; }
    __syncthreads();
    for (int o = t; o < 512; o += 256) {
        int d = o >> 4, m = o & 15, l = lmap(m);
        float s = 0.f;
        const float* wa = &wsk[l * 1024 + d];
        const float* wb = &wos[l * 1024 + d];
#pragma unroll
        for (int c = 0; c < 32; c++) s += hs[c * 16 + m] * wa[c * 32] + as[c * 16 + m] * wb[c * 32];
        hn[o] = s;
    }
    __syncthreads();
    if (t < 128) {
        int d = t >> 2, l = t & 3;
        int m0 = l * l, cnt = 2 * l + 1;
        float s = 1e-12f;
        for (int m = m0; m < m0 + cnt; m++) { float v = hn[d * 16 + m]; s += v * v; }
        float nr = sqrtf(s);
        float phi = fmaxf(nr * gw[(layer * 4 + l) * 32 + d] + gb[(layer * 4 + l) * 32 + d], 0.f);
        scale[d * 4 + l] = phi / (nr + 1e-6f);
    }
    __syncthreads();
    for (int o = t; o < 512; o += 256) {
        int d = o >> 4, m = o & 15, l = lmap(m);
        hnew[n * 512 + o] = hn[o] * scale[d * 4 + l];
    }
}

// ---------------- output stage node pre: wq2, U -----------------------------------
__global__ __launch_bounds__(256) void k_out_pre(
    const float* __restrict__ h, const float* __restrict__ WqO,
    const float* __restrict__ WkO, const float* __restrict__ WvO,
    float* __restrict__ wq2, float* __restrict__ U)
{
    __shared__ float hs[512];
    __shared__ float wvs[8192];
    __shared__ float qs[64];
    int n = blockIdx.x, t = threadIdx.x;
    for (int o = t; o < 512; o += 256) hs[o] = h[n * 512 + o];
    for (int o = t; o < 8192; o += 256) wvs[o] = WvO[o];
    __syncthreads();
    if (t < 64) {
        float s = 0.f;
#pragma unroll
        for (int c = 0; c < 32; c++) s += hs[c * 16] * WqO[c * 64 + t];
        qs[t] = s;
    }
    __syncthreads();
    if (t < 32) {
        float s = 0.f;
#pragma unroll
        for (int j = 0; j < 64; j++) s += WkO[t * 64 + j] * qs[j];
        wq2[n * 32 + t] = s;
    }
    for (int o = t; o < 1024; o += 256) {
        int m = o >> 6, j = o & 63, l = lmap(m);
        float s = 0.f;
        const float* wb = &wvs[l * 2048 + j];
#pragma unroll
        for (int c = 0; c < 32; c++) s += hs[c * 16 + m] * wb[c * 64];
        U[n * 1024 + o] = s;
    }
}

// ---------------- output stage edge kernel ---------------------------------------
__global__ __launch_bounds__(256) void k_out_edge(
    const float* __restrict__ x, const float* __restrict__ w1o,
    const float* __restrict__ b1o, const float* __restrict__ wq2,
    const float* __restrict__ roW, const float* __restrict__ U,
    float* __restrict__ agg64)
{
    __shared__ float xs[384];
    __shared__ float w1s[512];
    __shared__ float b1s[32];
    __shared__ float wq2s[32];
    __shared__ float ros[8192];
    __shared__ float rhs[128 * 33];  // overlaid later as aggred[4][64]
    __shared__ float yss[128 * 17];
    __shared__ float alphas[128];
    __shared__ float red[256];
    __shared__ float sh_inv;

    int n = blockIdx.x, t = threadIdx.x;
    int g = n >> 7, b = n & 127;
    int gbase = g << 7;

    for (int o = t; o < 384; o += 256) xs[o] = x[gbase * 3 + o];
    for (int o = t; o < 512; o += 256) w1s[o] = w1o[o];
    if (t < 32) { b1s[t] = b1o[t]; wq2s[t] = wq2[n * 32 + t]; }
    for (int o = t; o < 8192; o += 256) ros[o] = roW[o];
    __syncthreads();

    if (t < 128) {
        int a = t;
        float rx = xs[b * 3 + 0] - xs[a * 3 + 0];
        float ry = xs[b * 3 + 1] - xs[a * 3 + 1];
        float rz = xs[b * 3 + 2] - xs[a * 3 + 2];
        float dd = sqrtf(rx * rx + ry * ry + rz * rz + 1e-12f);
        float inv = 1.f / dd;
        float ys[16];
        sph16(rx * inv, ry * inv, rz * inv, ys);
#pragma unroll
        for (int m = 0; m < 16; m++) yss[a * 17 + m] = ys[m];
        float rbf[16];
#pragma unroll
        for (int j = 0; j < 16; j++) {
            float dc = dd - (4.f / 15.f) * j;
            rbf[j] = __expf(-2.f * dc * dc);
        }
        float logit = 0.f;
        for (int d = 0; d < 32; d++) {
            float s = b1s[d];
#pragma unroll
            for (int j = 0; j < 16; j++) s += rbf[j] * w1s[j * 32 + d];
            s = fmaxf(s, 0.f);
            rhs[a * 33 + d] = s;
            logit += s * wq2s[d];
        }
        alphas[a] = logit * 0.125f;  // 1/sqrt(64)
    }
    __syncthreads();

    red[t] = (t < 128 && t != b) ? alphas[t] : -1e30f;
    __syncthreads();
    for (int s = 128; s > 0; s >>= 1) { if (t < s) red[t] = fmaxf(red[t], red[t + s]); __syncthreads(); }
    float mx = red[0];
    __syncthreads();
    float e = (t < 128 && t != b) ? __expf(alphas[t] - mx) : 0.f;
    red[t] = e;
    __syncthreads();
    for (int s = 128; s > 0; s >>= 1) { if (t < s) red[t] += red[t + s]; __syncthreads(); }
    if (t == 0) sh_inv = 1.f / red[0];
    if (t < 128) alphas[t] = e;
    __syncthreads();

    int grp = t >> 6, j = t & 63;
    float acc = 0.f;
    for (int it = 0; it < 32; ++it) {
        int a = grp * 32 + it;
        float w = alphas[a];
        if (w == 0.f) continue;
        const float* Un = U + (gbase + a) * 1024 + j;
        const float* rha = &rhs[a * 33];
        const float* ysa = &yss[a * 17];
        float s = 0.f;
        // l = 0
        {
            float ro = 0.f;
#pragma unroll
            for (int c = 0; c < 32; c++) ro += rha[c] * ros[0 * 2048 + c * 64 + j];
            s += (ysa[0] * Un[0]) * ro;
        }
        // l = 1
        {
            float ro = 0.f, cv = 0.f;
#pragma unroll
            for (int c = 0; c < 32; c++) ro += rha[c] * ros[1 * 2048 + c * 64 + j];
#pragma unroll
            for (int m = 1; m < 4; m++) cv += ysa[m] * Un[m * 64];
            s += cv * ro;
        }
        // l = 2
        {
            float ro = 0.f, cv = 0.f;
#pragma unroll
            for (int c = 0; c < 32; c++) ro += rha[c] * ros[2 * 2048 + c * 64 + j];
#pragma unroll
            for (int m = 4; m < 9; m++) cv += ysa[m] * Un[m * 64];
            s += cv * ro;
        }
        // l = 3
        {
            float ro = 0.f, cv = 0.f;
#pragma unroll
            for (int c = 0; c < 32; c++) ro += rha[c] * ros[3 * 2048 + c * 64 + j];
#pragma unroll
            for (int m = 9; m < 16; m++) cv += ysa[m] * Un[m * 64];
            s += cv * ro;
        }
        acc += w * s;
    }
    __syncthreads();
    float* aggred = rhs;  // reuse
    aggred[grp * 64 + j] = acc;
    __syncthreads();
    if (t < 64) {
        float s = aggred[t] + aggred[64 + t] + aggred[128 + t] + aggred[192 + t];
        agg64[n * 64 + t] = s * sh_inv;
    }
}

// ---------------- output stage node post: hout ------------------------------------
__global__ __launch_bounds__(256) void k_out_post(
    const float* __restrict__ agg64, const float* __restrict__ h,
    const float* __restrict__ WoO, const float* __restrict__ WskipO,
    float* __restrict__ hout)
{
    int id = blockIdx.x * 256 + threadIdx.x;
    int n = id >> 6, j = id & 63;
    float s = 0.f;
    const float* ar = agg64 + n * 64;
#pragma unroll
    for (int c = 0; c < 64; c++) s += ar[c] * WoO[c * 64 + j];
    const float* hr = h + n * 512;
#pragma unroll
    for (int c = 0; c < 32; c++) s += hr[c * 16] * WskipO[c * 64 + j];
    hout[id] = s;
}

// ---------------- final: pool + MLP ------------------------------------------------
__global__ __launch_bounds__(64) void k_final(
    const float* __restrict__ hout, const float* __restrict__ Whid,
    const float* __restrict__ bhid, const float* __restrict__ Wout,
    const float* __restrict__ bout, float* __restrict__ out)
{
    __shared__ float pooled[64], hid[64];
    int g = blockIdx.x, t = threadIdx.x;
    float s = 0.f;
    for (int p = 0; p < 128; p++) s += hout[(g * 128 + p) * 64 + t];
    pooled[t] = s * (1.f / 128.f);
    __syncthreads();
    float hv = bhid[t];
#pragma unroll
    for (int c = 0; c < 64; c++) hv += pooled[c] * Whid[c * 64 + t];
    hid[t] = fmaxf(hv, 0.f);
    __syncthreads();
    if (t < 15) {
        float o = bout[t];
#pragma unroll
        for (int c = 0; c < 64; c++) o += hid[c] * Wout[c * 15 + t];
        out[g * 15 + t] = o;
    }
}

extern "C" void kernel_launch(void* const* d_in, const int* in_sizes, int n_in,
                              void* d_out, int out_size, void* d_ws, size_t ws_size,
                              hipStream_t stream) {
    const float* x      = (const float*)d_in[0];
    const float* w1     = (const float*)d_in[1];
    const float* b1     = (const float*)d_in[2];
    const float* rW     = (const float*)d_in[3];
    const float* sW     = (const float*)d_in[4];
    const float* Wv     = (const float*)d_in[5];
    const float* Wq     = (const float*)d_in[6];
    const float* Wk     = (const float*)d_in[7];
    const float* Wo     = (const float*)d_in[8];
    const float* Wskip  = (const float*)d_in[9];
    const float* gw     = (const float*)d_in[10];
    const float* gb     = (const float*)d_in[11];
    const float* w1o    = (const float*)d_in[12];
    const float* b1o    = (const float*)d_in[13];
    const float* roW    = (const float*)d_in[14];
    const float* WvO    = (const float*)d_in[15];
    const float* WqO    = (const float*)d_in[16];
    const float* WkO    = (const float*)d_in[17];
    const float* WoO    = (const float*)d_in[18];
    const float* WskipO = (const float*)d_in[19];
    const float* Whid   = (const float*)d_in[20];
    const float* bhid   = (const float*)d_in[21];
    const float* Wout   = (const float*)d_in[22];
    const float* bout   = (const float*)d_in[23];
    float* out = (float*)d_out;

    float* ws = (float*)d_ws;
    float* h0    = ws;
    float* h1    = h0 + NNODE * 512;
    float* vpre  = h1 + NNODE * 512;
    float* wqk   = vpre + NNODE * 512;
    float* agg   = wqk + NNODE * 32;
    float* wq2   = agg + NNODE * 512;
    float* U     = wq2 + NNODE * 32;
    float* agg64 = U + NNODE * 1024;
    float* hout  = agg64 + NNODE * 64;

    hipMemsetAsync(h0, 0, NNODE * 512 * sizeof(float), stream);

    for (int i = 0; i < 4; i++) {
        const float* hc = (i & 1) ? h1 : h0;
        float* hn = (i & 1) ? h0 : h1;
        k_node_pre<<<NNODE, 256, 0, stream>>>(hc, Wv, Wq, Wk, vpre, wqk, i);
        k_edge<<<NNODE, 256, 0, stream>>>(x, hc, vpre, wqk, w1, b1, rW, sW, agg, i);
        k_node_post<<<NNODE, 256, 0, stream>>>(hc, agg, Wskip, Wo, gw, gb, hn, i);
    }
    // final h in h0
    k_out_pre<<<NNODE, 256, 0, stream>>>(h0, WqO, WkO, WvO, wq2, U);
    k_out_edge<<<NNODE, 256, 0, stream>>>(x, w1o, b1o, wq2, roW, U, agg64);
    k_out_post<<<NNODE * 64 / 256, 256, 0, stream>>>(agg64, h0, WoO, WskipO, hout);
    k_final<<<NGRAPH, 64, 0, stream>>>(hout, Whid, bhid, Wout, bout, out);
}

// Round 2
// 638.004 us; speedup vs baseline: 1.9584x; 1.9584x over previous
//
#include <hip/hip_runtime.h>
#include <hip/hip_bf16.h>

#define NNODE 2048
#define NGRAPH 16

__device__ __forceinline__ int lmap(int m) { return m == 0 ? 0 : (m < 4 ? 1 : (m < 9 ? 2 : 3)); }

__device__ __forceinline__ float f4get(const float4& v, int j) {
    return j == 0 ? v.x : (j == 1 ? v.y : (j == 2 ? v.z : v.w));
}

__device__ __forceinline__ void sph16(float x, float y, float z, float* Y) {
    Y[0] = 0.28209479177f;
    Y[1] = 0.4886025119f * y; Y[2] = 0.4886025119f * z; Y[3] = 0.4886025119f * x;
    Y[4] = 1.09254843059f * x * y;
    Y[5] = 1.09254843059f * y * z;
    Y[6] = 0.31539156525f * (3.f * z * z - 1.f);
    Y[7] = 1.09254843059f * x * z;
    Y[8] = 0.54627421529f * (x * x - y * y);
    Y[9]  = 0.59004358992f * y * (3.f * x * x - y * y);
    Y[10] = 2.89061144264f * x * y * z;
    Y[11] = 0.45704579946f * y * (5.f * z * z - 1.f);
    Y[12] = 0.37317633259f * z * (5.f * z * z - 3.f);
    Y[13] = 0.45704579946f * x * (5.f * z * z - 1.f);
    Y[14] = 1.44530572132f * z * (x * x - y * y);
    Y[15] = 0.59004358992f * x * (x * x - 3.f * y * y);
}

// One fused layer: edge-attention aggregate + node post (skip+Wo+norm-gate) +
// next-layer node pre (vpre/wqk)  [or output-stage pre (U/wq2) when last=1].
__global__ __launch_bounds__(256, 2) void k_layer(
    const float* __restrict__ x, const float* __restrict__ h,
    const float* __restrict__ vpre, const float* __restrict__ wqk,
    const float* __restrict__ w1, const float* __restrict__ b1,
    const float* __restrict__ rW, const float* __restrict__ sW,
    const float* __restrict__ Wskip, const float* __restrict__ Wo,
    const float* __restrict__ gw, const float* __restrict__ gb,
    const float* __restrict__ Wv_n, const float* __restrict__ Wq_n, const float* __restrict__ Wk_n,
    const float* __restrict__ WvO, const float* __restrict__ WqO, const float* __restrict__ WkO,
    float* __restrict__ hnew, float* __restrict__ vpre_n, float* __restrict__ wqk_n,
    float* __restrict__ wq2, float* __restrict__ U,
    int layer, int last)
{
    __shared__ __align__(16) float rwsw[8192];      // [l][j][d][2] interleaved; later wsk|wo; later Wv/WvO
    __shared__ __align__(16) float rhs[128 * 36];   // rh (stride 36); later P[8][528]
    __shared__ __align__(16) float yss[128 * 17];   // Ys; later hs[512]
    __shared__ __align__(16) float hnS[528];        // hn, layout [m*33+c]
    __shared__ __align__(16) float aggL[528];       // agg, layout [m*33+c]
    __shared__ float xs[384];
    __shared__ float w1s[512];
    __shared__ float b1s[32];
    __shared__ float wqks[32];
    __shared__ float alphas[128];
    __shared__ float red[256];
    __shared__ float scale[128];
    __shared__ float sh_inv;

    int n = blockIdx.x, t = threadIdx.x;
    int g = n >> 7, b = n & 127;
    int gbase = g << 7;

    for (int o = t; o < 384; o += 256) xs[o] = x[gbase * 3 + o];
    for (int o = t; o < 512; o += 256) w1s[o] = w1[layer * 512 + o];
    if (t < 32) { b1s[t] = b1[layer * 32 + t]; wqks[t] = wqk[n * 32 + t]; }
    for (int o = t; o < 4096; o += 256) {
        rwsw[o * 2] = rW[layer * 4096 + o];
        rwsw[o * 2 + 1] = sW[layer * 4096 + o];
    }
    __syncthreads();

    // ---- phase A: geometry, rh, raw logit ----
    if (t < 128) {
        int a = t;
        float rx = xs[b * 3 + 0] - xs[a * 3 + 0];
        float ry = xs[b * 3 + 1] - xs[a * 3 + 1];
        float rz = xs[b * 3 + 2] - xs[a * 3 + 2];
        float dd = sqrtf(rx * rx + ry * ry + rz * rz + 1e-12f);
        float inv = 1.f / dd;
        float ys[16];
        sph16(rx * inv, ry * inv, rz * inv, ys);
#pragma unroll
        for (int m = 0; m < 16; m++) yss[a * 17 + m] = ys[m];
        float rbf[16];
#pragma unroll
        for (int j = 0; j < 16; j++) {
            float dc = dd - (4.f / 15.f) * j;
            rbf[j] = __expf(-2.f * dc * dc);
        }
        float logit = 0.f;
        for (int d = 0; d < 32; d++) {
            float s = b1s[d];
#pragma unroll
            for (int j = 0; j < 16; j++) s = fmaf(rbf[j], w1s[j * 32 + d], s);
            s = fmaxf(s, 0.f);
            rhs[a * 36 + d] = s;
            logit = fmaf(s, wqks[d], logit);
        }
        alphas[a] = logit * 0.17677669529663687f;   // 1/sqrt(32)
    }
    __syncthreads();

    // ---- segment softmax over 127 valid edges ----
    red[t] = (t < 128 && t != b) ? alphas[t] : -1e30f;
    __syncthreads();
    for (int s2 = 128; s2 > 0; s2 >>= 1) { if (t < s2) red[t] = fmaxf(red[t], red[t + s2]); __syncthreads(); }
    float mx = red[0];
    __syncthreads();
    float e = (t < 128 && t != b) ? __expf(alphas[t] - mx) : 0.f;
    red[t] = e;
    __syncthreads();
    for (int s2 = 128; s2 > 0; s2 >>= 1) { if (t < s2) red[t] += red[t + s2]; __syncthreads(); }
    if (t == 0) sh_inv = 1.f / red[0];
    if (t < 128) alphas[t] = e;
    __syncthreads();

    // ---- pass 2: register-blocked R/S GEMM + weighted aggregate ----
    int grp = t >> 5, d = t & 31;
    float acc[16];
#pragma unroll
    for (int m = 0; m < 16; m++) acc[m] = 0.f;

    for (int chunk = 0; chunk < 2; chunk++) {
        int a0 = grp * 16 + chunk * 8;
        float R[8][4], S[8][4];
#pragma unroll
        for (int aa = 0; aa < 8; aa++)
#pragma unroll
            for (int l = 0; l < 4; l++) { R[aa][l] = 0.f; S[aa][l] = 0.f; }

#pragma unroll 2
        for (int jq = 0; jq < 8; jq++) {
            float4 rh4[8];
#pragma unroll
            for (int aa = 0; aa < 8; aa++)
                rh4[aa] = *reinterpret_cast<const float4*>(&rhs[(a0 + aa) * 36 + jq * 4]);
#pragma unroll
            for (int l = 0; l < 4; l++) {
#pragma unroll
                for (int jj = 0; jj < 4; jj++) {
                    float2 w2 = *reinterpret_cast<const float2*>(&rwsw[((l * 32 + jq * 4 + jj) * 32 + d) * 2]);
#pragma unroll
                    for (int aa = 0; aa < 8; aa++) {
                        float rv = f4get(rh4[aa], jj);
                        R[aa][l] = fmaf(rv, w2.x, R[aa][l]);
                        S[aa][l] = fmaf(rv, w2.y, S[aa][l]);
                    }
                }
            }
        }

        // epilogue over the 8 sources, 1-deep pipelined global loads
        int nb = (gbase + a0) * 512 + d * 16;
        const float4* vp4 = reinterpret_cast<const float4*>(vpre + nb);
        float4 u0 = vp4[0], u1 = vp4[1], u2 = vp4[2], u3 = vp4[3];
        float h0v = h[nb];
#pragma unroll
        for (int aa = 0; aa < 8; aa++) {
            float4 n0 = u0, n1 = u1, n2 = u2, n3 = u3; float nh = h0v;
            if (aa < 7) {
                int nb2 = (gbase + a0 + aa + 1) * 512 + d * 16;
                const float4* np4 = reinterpret_cast<const float4*>(vpre + nb2);
                n0 = np4[0]; n1 = np4[1]; n2 = np4[2]; n3 = np4[3];
                nh = h[nb2];
            }
            int a = a0 + aa;
            float w = alphas[a];
            if (w != 0.f) {
                const float* ysa = &yss[a * 17];
                float hb1 = h0v + 1.f;
                float sc0 = S[aa][0] * hb1, sc1 = S[aa][1] * hb1;
                float sc2 = S[aa][2] * hb1, sc3 = S[aa][3] * hb1;
                acc[0]  = fmaf(w, fmaf(u0.x, R[aa][0], sc0 * ysa[0]),  acc[0]);
                acc[1]  = fmaf(w, fmaf(u0.y, R[aa][1], sc1 * ysa[1]),  acc[1]);
                acc[2]  = fmaf(w, fmaf(u0.z, R[aa][1], sc1 * ysa[2]),  acc[2]);
                acc[3]  = fmaf(w, fmaf(u0.w, R[aa][1], sc1 * ysa[3]),  acc[3]);
                acc[4]  = fmaf(w, fmaf(u1.x, R[aa][2], sc2 * ysa[4]),  acc[4]);
                acc[5]  = fmaf(w, fmaf(u1.y, R[aa][2], sc2 * ysa[5]),  acc[5]);
                acc[6]  = fmaf(w, fmaf(u1.z, R[aa][2], sc2 * ysa[6]),  acc[6]);
                acc[7]  = fmaf(w, fmaf(u1.w, R[aa][2], sc2 * ysa[7]),  acc[7]);
                acc[8]  = fmaf(w, fmaf(u2.x, R[aa][2], sc2 * ysa[8]),  acc[8]);
                acc[9]  = fmaf(w, fmaf(u2.y, R[aa][3], sc3 * ysa[9]),  acc[9]);
                acc[10] = fmaf(w, fmaf(u2.z, R[aa][3], sc3 * ysa[10]), acc[10]);
                acc[11] = fmaf(w, fmaf(u2.w, R[aa][3], sc3 * ysa[11]), acc[11]);
                acc[12] = fmaf(w, fmaf(u3.x, R[aa][3], sc3 * ysa[12]), acc[12]);
                acc[13] = fmaf(w, fmaf(u3.y, R[aa][3], sc3 * ysa[13]), acc[13]);
                acc[14] = fmaf(w, fmaf(u3.z, R[aa][3], sc3 * ysa[14]), acc[14]);
                acc[15] = fmaf(w, fmaf(u3.w, R[aa][3], sc3 * ysa[15]), acc[15]);
            }
            u0 = n0; u1 = n1; u2 = n2; u3 = n3; h0v = nh;
        }
    }
    __syncthreads();   // all pass-2 LDS reads (rhs/rwsw/yss) done

    // partials into P (overlay rhs); stage h[n] (overlay yss); stage Wskip|Wo into rwsw
    float* P = rhs;
#pragma unroll
    for (int m = 0; m < 16; m++) P[grp * 528 + m * 33 + d] = acc[m];
    float* hs = yss;
    for (int o = t; o < 512; o += 256) hs[o] = h[n * 512 + o];
    for (int o = t; o < 4096; o += 256) {
        rwsw[o] = Wskip[layer * 4096 + o];
        rwsw[4096 + o] = Wo[layer * 4096 + o];
    }
    __syncthreads();

    // reduce partials -> aggL[m*33+c]
    float invs = sh_inv;
    for (int o = t; o < 512; o += 256) {
        int m = o >> 5, c = o & 31;
        float s = 0.f;
#pragma unroll
        for (int gg = 0; gg < 8; gg++) s += P[gg * 528 + m * 33 + c];
        aggL[m * 33 + c] = s * invs;
    }
    __syncthreads();

    // post GEMM: hn = h@Wskip + agg@Wo   (thread mapping o = m*32+d)
    for (int o = t; o < 512; o += 256) {
        int m = o >> 5, dd = o & 31, l = lmap(m);
        float s = 0.f;
        const float* wa = &rwsw[l * 1024 + dd];
        const float* wb = &rwsw[4096 + l * 1024 + dd];
        const float* hrow = &hs[m];
        const float* arow = &aggL[m * 33];
#pragma unroll
        for (int c = 0; c < 32; c++) {
            s = fmaf(hrow[c * 16], wa[c * 32], s);
            s = fmaf(arow[c],      wb[c * 32], s);
        }
        hnS[m * 33 + dd] = s;
    }
    __syncthreads();

    // norm gate
    if (t < 128) {
        int dd = t >> 2, l = t & 3;
        int m0 = l * l, cnt = 2 * l + 1;
        float s = 1e-12f;
        for (int m = m0; m < m0 + cnt; m++) { float v = hnS[m * 33 + dd]; s = fmaf(v, v, s); }
        float nr = sqrtf(s);
        float phi = fmaxf(nr * gw[(layer * 4 + l) * 32 + dd] + gb[(layer * 4 + l) * 32 + dd], 0.f);
        scale[dd * 4 + l] = phi / (nr + 1e-6f);
    }
    __syncthreads();

    // apply gate, write hnew (global, layout [c][m]); stage next-stage value weights
    for (int o = t; o < 512; o += 256) {
        int dd = o >> 4, m = o & 15;
        float v = hnS[m * 33 + dd] * scale[dd * 4 + lmap(m)];
        hnew[n * 512 + o] = v;
        hnS[m * 33 + dd] = v;
    }
    int wsz = last ? 8192 : 4096;
    for (int o = t; o < wsz; o += 256) rwsw[o] = last ? WvO[o] : Wv_n[o];
    __syncthreads();

    if (!last) {
        // vpre_{i+1}[n][d][m] = sum_c hnew[c][m] * Wv_{i+1}[l][c][d]
        for (int o = t; o < 512; o += 256) {
            int dd = o >> 4, m = o & 15, l = lmap(m);
            float s = 0.f;
            const float* wv = &rwsw[l * 1024 + dd];
            const float* hrow = &hnS[m * 33];
#pragma unroll
            for (int c = 0; c < 32; c++) s = fmaf(hrow[c], wv[c * 32], s);
            vpre_n[n * 512 + o] = s;
        }
        if (t < 32) {
            float s = 0.f;
#pragma unroll
            for (int c = 0; c < 32; c++) s = fmaf(hnS[c], Wq_n[c * 32 + t], s);
            red[t] = s;
        }
        __syncthreads();
        if (t < 32) {
            float s = 0.f;
#pragma unroll
            for (int j = 0; j < 32; j++) s = fmaf(Wk_n[t * 32 + j], red[j], s);
            wqk_n[n * 32 + t] = s;
        }
    } else {
        // U[n][j][m] = sum_c hnew[c][m] * WvO[l][c][j]
        for (int o = t; o < 1024; o += 256) {
            int j = o >> 4, m = o & 15, l = lmap(m);
            float s = 0.f;
            const float* wv = &rwsw[l * 2048 + j];
            const float* hrow = &hnS[m * 33];
#pragma unroll
            for (int c = 0; c < 32; c++) s = fmaf(hrow[c], wv[c * 64], s);
            U[n * 1024 + o] = s;
        }
        if (t < 64) {
            float s = 0.f;
#pragma unroll
            for (int c = 0; c < 32; c++) s = fmaf(hnS[c], WqO[c * 64 + t], s);
            red[t] = s;
        }
        __syncthreads();
        if (t < 32) {
            float s = 0.f;
#pragma unroll
            for (int j = 0; j < 64; j++) s = fmaf(WkO[t * 64 + j], red[j], s);
            wq2[n * 32 + t] = s;
        }
    }
}

// Output-stage edge kernel + fused out_post (hout)
__global__ __launch_bounds__(256, 2) void k_out_edge(
    const float* __restrict__ x, const float* __restrict__ h,
    const float* __restrict__ w1o, const float* __restrict__ b1o,
    const float* __restrict__ wq2, const float* __restrict__ roW,
    const float* __restrict__ U, const float* __restrict__ WoO,
    const float* __restrict__ WskipO, float* __restrict__ hout)
{
    __shared__ __align__(16) float ros[8192];       // [l][c][j]
    __shared__ __align__(16) float rhs[128 * 36];
    __shared__ __align__(16) float yss[128 * 17];
    __shared__ float xs[384];
    __shared__ float w1s[512];
    __shared__ float b1s[32];
    __shared__ float wq2s[32];
    __shared__ float alphas[128];
    __shared__ float red[256];
    __shared__ float agg64s[64];
    __shared__ float sh_inv;

    int n = blockIdx.x, t = threadIdx.x;
    int g = n >> 7, b = n & 127;
    int gbase = g << 7;

    for (int o = t; o < 384; o += 256) xs[o] = x[gbase * 3 + o];
    for (int o = t; o < 512; o += 256) w1s[o] = w1o[o];
    if (t < 32) { b1s[t] = b1o[t]; wq2s[t] = wq2[n * 32 + t]; }
    for (int o = t; o < 8192; o += 256) ros[o] = roW[o];
    __syncthreads();

    if (t < 128) {
        int a = t;
        float rx = xs[b * 3 + 0] - xs[a * 3 + 0];
        float ry = xs[b * 3 + 1] - xs[a * 3 + 1];
        float rz = xs[b * 3 + 2] - xs[a * 3 + 2];
        float dd = sqrtf(rx * rx + ry * ry + rz * rz + 1e-12f);
        float inv = 1.f / dd;
        float ys[16];
        sph16(rx * inv, ry * inv, rz * inv, ys);
#pragma unroll
        for (int m = 0; m < 16; m++) yss[a * 17 + m] = ys[m];
        float rbf[16];
#pragma unroll
        for (int j = 0; j < 16; j++) {
            float dc = dd - (4.f / 15.f) * j;
            rbf[j] = __expf(-2.f * dc * dc);
        }
        float logit = 0.f;
        for (int d = 0; d < 32; d++) {
            float s = b1s[d];
#pragma unroll
            for (int j = 0; j < 16; j++) s = fmaf(rbf[j], w1s[j * 32 + d], s);
            s = fmaxf(s, 0.f);
            rhs[a * 36 + d] = s;
            logit = fmaf(s, wq2s[d], logit);
        }
        alphas[a] = logit * 0.125f;   // 1/sqrt(64)
    }
    __syncthreads();

    red[t] = (t < 128 && t != b) ? alphas[t] : -1e30f;
    __syncthreads();
    for (int s2 = 128; s2 > 0; s2 >>= 1) { if (t < s2) red[t] = fmaxf(red[t], red[t + s2]); __syncthreads(); }
    float mx = red[0];
    __syncthreads();
    float e = (t < 128 && t != b) ? __expf(alphas[t] - mx) : 0.f;
    red[t] = e;
    __syncthreads();
    for (int s2 = 128; s2 > 0; s2 >>= 1) { if (t < s2) red[t] += red[t + s2]; __syncthreads(); }
    if (t == 0) sh_inv = 1.f / red[0];
    if (t < 128) alphas[t] = e;
    __syncthreads();

    int grp = t >> 6, j = t & 63;
    float accO = 0.f;
    for (int chunk = 0; chunk < 4; chunk++) {
        int a0 = grp * 32 + chunk * 8;
        float RO[8][4];
#pragma unroll
        for (int aa = 0; aa < 8; aa++)
#pragma unroll
            for (int l = 0; l < 4; l++) RO[aa][l] = 0.f;

#pragma unroll 2
        for (int cq = 0; cq < 8; cq++) {
            float4 rh4[8];
#pragma unroll
            for (int aa = 0; aa < 8; aa++)
                rh4[aa] = *reinterpret_cast<const float4*>(&rhs[(a0 + aa) * 36 + cq * 4]);
#pragma unroll
            for (int l = 0; l < 4; l++) {
#pragma unroll
                for (int cc = 0; cc < 4; cc++) {
                    float wv = ros[(l * 32 + cq * 4 + cc) * 64 + j];
#pragma unroll
                    for (int aa = 0; aa < 8; aa++)
                        RO[aa][l] = fmaf(f4get(rh4[aa], cc), wv, RO[aa][l]);
                }
            }
        }

        const float4* Up = reinterpret_cast<const float4*>(U + (gbase + a0) * 1024 + j * 16);
        float4 u0 = Up[0], u1 = Up[1], u2 = Up[2], u3 = Up[3];
#pragma unroll
        for (int aa = 0; aa < 8; aa++) {
            float4 n0 = u0, n1 = u1, n2 = u2, n3 = u3;
            if (aa < 7) {
                const float4* Np = reinterpret_cast<const float4*>(U + (gbase + a0 + aa + 1) * 1024 + j * 16);
                n0 = Np[0]; n1 = Np[1]; n2 = Np[2]; n3 = Np[3];
            }
            int a = a0 + aa;
            float w = alphas[a];
            if (w != 0.f) {
                const float* ysa = &yss[a * 17];
                float cv0 = ysa[0] * u0.x;
                float cv1 = fmaf(ysa[1], u0.y, fmaf(ysa[2], u0.z, ysa[3] * u0.w));
                float cv2 = fmaf(ysa[4], u1.x, fmaf(ysa[5], u1.y, fmaf(ysa[6], u1.z, fmaf(ysa[7], u1.w, ysa[8] * u2.x))));
                float cv3 = fmaf(ysa[9], u2.y, fmaf(ysa[10], u2.z, fmaf(ysa[11], u2.w,
                            fmaf(ysa[12], u3.x, fmaf(ysa[13], u3.y, fmaf(ysa[14], u3.z, ysa[15] * u3.w))))));
                float s = fmaf(cv0, RO[aa][0], fmaf(cv1, RO[aa][1], fmaf(cv2, RO[aa][2], cv3 * RO[aa][3])));
                accO = fmaf(w, s, accO);
            }
            u0 = n0; u1 = n1; u2 = n2; u3 = n3;
        }
    }
    red[t] = accO;
    __syncthreads();
    if (t < 64) agg64s[t] = (red[t] + red[64 + t] + red[128 + t] + red[192 + t]) * sh_inv;
    __syncthreads();

    if (t < 64) {
        float s = 0.f;
#pragma unroll
        for (int c = 0; c < 64; c++) s = fmaf(agg64s[c], WoO[c * 64 + t], s);
        const float* hr = &h[n * 512];
#pragma unroll
        for (int c = 0; c < 32; c++) s = fmaf(hr[c * 16], WskipO[c * 64 + t], s);
        hout[n * 64 + t] = s;
    }
}

__global__ __launch_bounds__(64) void k_final(
    const float* __restrict__ hout, const float* __restrict__ Whid,
    const float* __restrict__ bhid, const float* __restrict__ Wout,
    const float* __restrict__ bout, float* __restrict__ out)
{
    __shared__ float pooled[64], hid[64];
    int g = blockIdx.x, t = threadIdx.x;
    float s = 0.f;
    for (int p = 0; p < 128; p++) s += hout[(g * 128 + p) * 64 + t];
    pooled[t] = s * (1.f / 128.f);
    __syncthreads();
    float hv = bhid[t];
#pragma unroll
    for (int c = 0; c < 64; c++) hv = fmaf(pooled[c], Whid[c * 64 + t], hv);
    hid[t] = fmaxf(hv, 0.f);
    __syncthreads();
    if (t < 15) {
        float o = bout[t];
#pragma unroll
        for (int c = 0; c < 64; c++) o = fmaf(hid[c], Wout[c * 15 + t], o);
        out[g * 15 + t] = o;
    }
}

extern "C" void kernel_launch(void* const* d_in, const int* in_sizes, int n_in,
                              void* d_out, int out_size, void* d_ws, size_t ws_size,
                              hipStream_t stream) {
    const float* x      = (const float*)d_in[0];
    const float* w1     = (const float*)d_in[1];
    const float* b1     = (const float*)d_in[2];
    const float* rW     = (const float*)d_in[3];
    const float* sW     = (const float*)d_in[4];
    const float* Wv     = (const float*)d_in[5];
    const float* Wq     = (const float*)d_in[6];
    const float* Wk     = (const float*)d_in[7];
    const float* Wo     = (const float*)d_in[8];
    const float* Wskip  = (const float*)d_in[9];
    const float* gw     = (const float*)d_in[10];
    const float* gb     = (const float*)d_in[11];
    const float* w1o    = (const float*)d_in[12];
    const float* b1o    = (const float*)d_in[13];
    const float* roW    = (const float*)d_in[14];
    const float* WvO    = (const float*)d_in[15];
    const float* WqO    = (const float*)d_in[16];
    const float* WkO    = (const float*)d_in[17];
    const float* WoO    = (const float*)d_in[18];
    const float* WskipO = (const float*)d_in[19];
    const float* Whid   = (const float*)d_in[20];
    const float* bhid   = (const float*)d_in[21];
    const float* Wout   = (const float*)d_in[22];
    const float* bout   = (const float*)d_in[23];
    float* out = (float*)d_out;

    float* ws = (float*)d_ws;
    float* h0    = ws;                       // 2048*512
    float* h1    = h0 + NNODE * 512;
    float* vA    = h1 + NNODE * 512;         // vpre buffer A (+ wqkA contiguous)
    float* wqkA  = vA + NNODE * 512;
    float* vB    = wqkA + NNODE * 32;
    float* wqkB  = vB + NNODE * 512;
    float* wq2   = wqkB + NNODE * 32;
    float* U     = wq2 + NNODE * 32;         // 2048*1024
    float* hout  = U + NNODE * 1024;

    hipMemsetAsync(h0, 0, NNODE * 512 * sizeof(float), stream);
    hipMemsetAsync(vA, 0, (NNODE * 512 + NNODE * 32) * sizeof(float), stream);

    for (int i = 0; i < 4; i++) {
        const float* hc  = (i & 1) ? h1 : h0;
        float*       hn  = (i & 1) ? h0 : h1;
        const float* vin  = (i & 1) ? vB : vA;
        const float* qin  = (i & 1) ? wqkB : wqkA;
        float*       vout = (i & 1) ? vA : vB;
        float*       qout = (i & 1) ? wqkA : wqkB;
        int last = (i == 3);
        k_layer<<<NNODE, 256, 0, stream>>>(
            x, hc, vin, qin, w1, b1, rW, sW, Wskip, Wo, gw, gb,
            Wv + (last ? 0 : (i + 1) * 4096),
            Wq + (last ? 0 : (i + 1) * 1024),
            Wk + (last ? 0 : (i + 1) * 1024),
            WvO, WqO, WkO,
            hn, vout, qout, wq2, U, i, last);
    }
    // final h in h0
    k_out_edge<<<NNODE, 256, 0, stream>>>(x, h0, w1o, b1o, wq2, roW, U, WoO, WskipO, hout);
    k_out_post_unused: ;
    k_final<<<NGRAPH, 64, 0, stream>>>(hout, Whid, bhid, Wout, bout, out);
}

// Round 4
// 600.998 us; speedup vs baseline: 2.0790x; 1.0616x over previous
//
#include <hip/hip_runtime.h>
#include <hip/hip_bf16.h>
#include <hip/hip_fp16.h>

#define NNODE 2048
#define NGRAPH 16

__device__ __forceinline__ int lmap(int m) { return m == 0 ? 0 : (m < 4 ? 1 : (m < 9 ? 2 : 3)); }

__device__ __forceinline__ float f4get(const float4& v, int j) {
    return j == 0 ? v.x : (j == 1 ? v.y : (j == 2 ? v.z : v.w));
}

// pack two floats as fp16 pair in a u32 (lo = a, hi = b)
__device__ __forceinline__ uint32_t f2h2(float a, float b) {
    __half2 h2 = __floats2half2_rn(a, b);
    return *reinterpret_cast<uint32_t*>(&h2);
}
__device__ __forceinline__ float2 h2f2(uint32_t u) {
    __half2 h2 = *reinterpret_cast<__half2*>(&u);
    return __half22float2(h2);
}

__device__ __forceinline__ void sph16(float x, float y, float z, float* Y) {
    Y[0] = 0.28209479177f;
    Y[1] = 0.4886025119f * y; Y[2] = 0.4886025119f * z; Y[3] = 0.4886025119f * x;
    Y[4] = 1.09254843059f * x * y;
    Y[5] = 1.09254843059f * y * z;
    Y[6] = 0.31539156525f * (3.f * z * z - 1.f);
    Y[7] = 1.09254843059f * x * z;
    Y[8] = 0.54627421529f * (x * x - y * y);
    Y[9]  = 0.59004358992f * y * (3.f * x * x - y * y);
    Y[10] = 2.89061144264f * x * y * z;
    Y[11] = 0.45704579946f * y * (5.f * z * z - 1.f);
    Y[12] = 0.37317633259f * z * (5.f * z * z - 3.f);
    Y[13] = 0.45704579946f * x * (5.f * z * z - 1.f);
    Y[14] = 1.44530572132f * z * (x * x - y * y);
    Y[15] = 0.59004358992f * x * (x * x - 3.f * y * y);
}

#define PROC_SRC(aa, u0, u1, u2, u3, h0v) { \
    int a_ = a0 + (aa); \
    float w_ = alphas[a_]; \
    if (w_ != 0.f) { \
        const float* ysa = &yss[a_ * 17]; \
        float hb1 = (h0v) + 1.f; \
        float sc0 = S[aa][0] * hb1, sc1 = S[aa][1] * hb1; \
        float sc2 = S[aa][2] * hb1, sc3 = S[aa][3] * hb1; \
        acc[0]  = fmaf(w_, fmaf((u0).x, R[aa][0], sc0 * ysa[0]),  acc[0]); \
        acc[1]  = fmaf(w_, fmaf((u0).y, R[aa][1], sc1 * ysa[1]),  acc[1]); \
        acc[2]  = fmaf(w_, fmaf((u0).z, R[aa][1], sc1 * ysa[2]),  acc[2]); \
        acc[3]  = fmaf(w_, fmaf((u0).w, R[aa][1], sc1 * ysa[3]),  acc[3]); \
        acc[4]  = fmaf(w_, fmaf((u1).x, R[aa][2], sc2 * ysa[4]),  acc[4]); \
        acc[5]  = fmaf(w_, fmaf((u1).y, R[aa][2], sc2 * ysa[5]),  acc[5]); \
        acc[6]  = fmaf(w_, fmaf((u1).z, R[aa][2], sc2 * ysa[6]),  acc[6]); \
        acc[7]  = fmaf(w_, fmaf((u1).w, R[aa][2], sc2 * ysa[7]),  acc[7]); \
        acc[8]  = fmaf(w_, fmaf((u2).x, R[aa][2], sc2 * ysa[8]),  acc[8]); \
        acc[9]  = fmaf(w_, fmaf((u2).y, R[aa][3], sc3 * ysa[9]),  acc[9]); \
        acc[10] = fmaf(w_, fmaf((u2).z, R[aa][3], sc3 * ysa[10]), acc[10]); \
        acc[11] = fmaf(w_, fmaf((u2).w, R[aa][3], sc3 * ysa[11]), acc[11]); \
        acc[12] = fmaf(w_, fmaf((u3).x, R[aa][3], sc3 * ysa[12]), acc[12]); \
        acc[13] = fmaf(w_, fmaf((u3).y, R[aa][3], sc3 * ysa[13]), acc[13]); \
        acc[14] = fmaf(w_, fmaf((u3).z, R[aa][3], sc3 * ysa[14]), acc[14]); \
        acc[15] = fmaf(w_, fmaf((u3).w, R[aa][3], sc3 * ysa[15]), acc[15]); \
    } }

// One fused layer. 3 blocks/CU (LDS ~49KB).
__global__ __launch_bounds__(256, 3) void k_layer(
    const float* __restrict__ x, const float* __restrict__ h,
    const float* __restrict__ vpre, const float* __restrict__ wqk,
    const float* __restrict__ w1, const float* __restrict__ b1,
    const float* __restrict__ rW, const float* __restrict__ sW,
    const float* __restrict__ Wskip, const float* __restrict__ Wo,
    const float* __restrict__ gw, const float* __restrict__ gb,
    const float* __restrict__ Wv_n, const float* __restrict__ Wq_n, const float* __restrict__ Wk_n,
    const float* __restrict__ WvO, const float* __restrict__ WqO, const float* __restrict__ WkO,
    float* __restrict__ hnew, float* __restrict__ vpre_n, float* __restrict__ wqk_n,
    float* __restrict__ wq2, float* __restrict__ U,
    int layer, int last)
{
    __shared__ uint32_t rwswP[4096];             // fp16 pair (rW,sW); later float-bits Wo / Wv_n / WvO-hi
    __shared__ __align__(16) float rhs[128 * 36]; // rh; later P[8][528]; later wsk / WvO-lo
    __shared__ __align__(16) float yss[128 * 17]; // Ys; later hs[512]
    __shared__ __align__(16) float ub[1056];      // phase A: xs[384]|w1s[512]; post: hnS[528]|aggL[528]
    __shared__ float b1s[32];
    __shared__ float wqks[32];
    __shared__ float alphas[128];
    __shared__ float red[256];
    __shared__ float scale[128];
    __shared__ float sh_inv;

    int n = blockIdx.x, t = threadIdx.x;
    int g = n >> 7, b = n & 127;
    int gbase = g << 7;

    float* xs = ub;           // [384]
    float* w1s = ub + 384;    // [512]

    for (int o = t; o < 384; o += 256) xs[o] = x[gbase * 3 + o];
    for (int o = t; o < 512; o += 256) w1s[o] = w1[layer * 512 + o];
    if (t < 32) { b1s[t] = b1[layer * 32 + t]; wqks[t] = wqk[n * 32 + t]; }
    for (int o = t; o < 4096; o += 256)
        rwswP[o] = f2h2(rW[layer * 4096 + o], sW[layer * 4096 + o]);
    __syncthreads();

    // ---- phase A: geometry, rh, partial logit (all 256 threads; 2 d-halves) ----
    {
        int a = t & 127, dh = t >> 7;
        float rx = xs[b * 3 + 0] - xs[a * 3 + 0];
        float ry = xs[b * 3 + 1] - xs[a * 3 + 1];
        float rz = xs[b * 3 + 2] - xs[a * 3 + 2];
        float dd = sqrtf(rx * rx + ry * ry + rz * rz + 1e-12f);
        float inv = 1.f / dd;
        float ys[16];
        sph16(rx * inv, ry * inv, rz * inv, ys);
        if (dh == 0) {
#pragma unroll
            for (int m = 0; m < 16; m++) yss[a * 17 + m] = ys[m];
        }
        float rbf[16];
#pragma unroll
        for (int j = 0; j < 16; j++) {
            float dc = dd - (4.f / 15.f) * j;
            rbf[j] = __expf(-2.f * dc * dc);
        }
        float lpart = 0.f;
        int d0 = dh * 16;
        for (int d2 = 0; d2 < 16; d2++) {
            int d = d0 + d2;
            float s = b1s[d];
#pragma unroll
            for (int j = 0; j < 16; j++) s = fmaf(rbf[j], w1s[j * 32 + d], s);
            s = fmaxf(s, 0.f);
            rhs[a * 36 + d] = s;
            lpart = fmaf(s, wqks[d], lpart);
        }
        red[t] = lpart;
    }
    __syncthreads();
    if (t < 128) alphas[t] = (red[t] + red[t + 128]) * 0.17677669529663687f; // 1/sqrt(32)
    __syncthreads();

    // ---- segment softmax over 127 valid edges ----
    red[t] = (t < 128 && t != b) ? alphas[t] : -1e30f;
    __syncthreads();
    for (int s2 = 128; s2 > 0; s2 >>= 1) { if (t < s2) red[t] = fmaxf(red[t], red[t + s2]); __syncthreads(); }
    float mx = red[0];
    __syncthreads();
    float e = (t < 128 && t != b) ? __expf(alphas[t] - mx) : 0.f;
    red[t] = e;
    __syncthreads();
    for (int s2 = 128; s2 > 0; s2 >>= 1) { if (t < s2) red[t] += red[t + s2]; __syncthreads(); }
    if (t == 0) sh_inv = 1.f / red[0];
    if (t < 128) alphas[t] = e;
    __syncthreads();

    // ---- pass 2: register-blocked R/S GEMM + weighted aggregate ----
    int grp = t >> 5, d = t & 31;
    float acc[16];
#pragma unroll
    for (int m = 0; m < 16; m++) acc[m] = 0.f;

    for (int chunk = 0; chunk < 2; chunk++) {
        int a0 = grp * 16 + chunk * 8;
        float R[8][4], S[8][4];
#pragma unroll
        for (int aa = 0; aa < 8; aa++)
#pragma unroll
            for (int l = 0; l < 4; l++) { R[aa][l] = 0.f; S[aa][l] = 0.f; }

#pragma unroll 2
        for (int jq = 0; jq < 8; jq++) {
            float4 rh4[8];
#pragma unroll
            for (int aa = 0; aa < 8; aa++)
                rh4[aa] = *reinterpret_cast<const float4*>(&rhs[(a0 + aa) * 36 + jq * 4]);
#pragma unroll
            for (int l = 0; l < 4; l++) {
#pragma unroll
                for (int jj = 0; jj < 4; jj++) {
                    float2 w2 = h2f2(rwswP[(l * 32 + jq * 4 + jj) * 32 + d]);
#pragma unroll
                    for (int aa = 0; aa < 8; aa++) {
                        float rv = f4get(rh4[aa], jj);
                        R[aa][l] = fmaf(rv, w2.x, R[aa][l]);
                        S[aa][l] = fmaf(rv, w2.y, S[aa][l]);
                    }
                }
            }
        }

        // epilogue: 2-deep double-buffered global loads
        float4 A0, A1, A2, A3, B0, B1, B2, B3; float Ah, Bh;
        {
            int nb = (gbase + a0) * 512 + d * 16;
            const float4* p4 = reinterpret_cast<const float4*>(vpre + nb);
            A0 = p4[0]; A1 = p4[1]; A2 = p4[2]; A3 = p4[3]; Ah = h[nb];
            int nb2 = (gbase + a0 + 1) * 512 + d * 16;
            const float4* q4 = reinterpret_cast<const float4*>(vpre + nb2);
            B0 = q4[0]; B1 = q4[1]; B2 = q4[2]; B3 = q4[3]; Bh = h[nb2];
        }
#pragma unroll
        for (int ap = 0; ap < 4; ap++) {
            int aa = ap * 2;
            {
                float4 u0 = A0, u1 = A1, u2 = A2, u3 = A3; float h0v = Ah;
                if (ap < 3) {
                    int nb2 = (gbase + a0 + aa + 2) * 512 + d * 16;
                    const float4* p4 = reinterpret_cast<const float4*>(vpre + nb2);
                    A0 = p4[0]; A1 = p4[1]; A2 = p4[2]; A3 = p4[3]; Ah = h[nb2];
                }
                PROC_SRC(aa, u0, u1, u2, u3, h0v)
            }
            {
                float4 u0 = B0, u1 = B1, u2 = B2, u3 = B3; float h0v = Bh;
                if (ap < 3) {
                    int nb2 = (gbase + a0 + aa + 3) * 512 + d * 16;
                    const float4* p4 = reinterpret_cast<const float4*>(vpre + nb2);
                    B0 = p4[0]; B1 = p4[1]; B2 = p4[2]; B3 = p4[3]; Bh = h[nb2];
                }
                PROC_SRC(aa + 1, u0, u1, u2, u3, h0v)
            }
        }
    }
    __syncthreads();   // all pass-2 LDS reads (rhs/rwswP/yss) done

    // S1: partials into P (overlay rhs); stage h[n] (overlay yss); stage Wo (float bits in rwswP)
    float* P = rhs;
#pragma unroll
    for (int m = 0; m < 16; m++) P[grp * 528 + m * 33 + d] = acc[m];
    float* hs = yss;
    for (int o = t; o < 512; o += 256) hs[o] = h[n * 512 + o];
    for (int o = t; o < 4096; o += 256) rwswP[o] = __float_as_uint(Wo[layer * 4096 + o]);
    __syncthreads();

    // S2: reduce partials -> aggL[m*33+c]
    float* hnS = ub;          // [528]
    float* aggL = ub + 528;   // [528]
    float invs = sh_inv;
    for (int o = t; o < 512; o += 256) {
        int m = o >> 5, c = o & 31;
        float s = 0.f;
#pragma unroll
        for (int gg = 0; gg < 8; gg++) s += P[gg * 528 + m * 33 + c];
        aggL[m * 33 + c] = s * invs;
    }
    __syncthreads();

    // S3: stage Wskip into rhs (fp32), P dead
    for (int o = t; o < 4096; o += 256) rhs[o] = Wskip[layer * 4096 + o];
    __syncthreads();

    // S4: post GEMM: hn = h@Wskip + agg@Wo
    for (int o = t; o < 512; o += 256) {
        int m = o >> 5, dd = o & 31, l = lmap(m);
        float s = 0.f;
        const float* wa = &rhs[l * 1024 + dd];
        const uint32_t* wb = &rwswP[l * 1024 + dd];
        const float* hrow = &hs[m];
        const float* arow = &aggL[m * 33];
#pragma unroll
        for (int c = 0; c < 32; c++) {
            s = fmaf(hrow[c * 16], wa[c * 32], s);
            s = fmaf(arow[c], __uint_as_float(wb[c * 32]), s);
        }
        hnS[m * 33 + dd] = s;
    }
    __syncthreads();

    // S5: norm gate compute + stage next-stage value weights
    if (t < 128) {
        int dd = t >> 2, l = t & 3;
        int m0 = l * l, cnt = 2 * l + 1;
        float s = 1e-12f;
        for (int m = m0; m < m0 + cnt; m++) { float v = hnS[m * 33 + dd]; s = fmaf(v, v, s); }
        float nr = sqrtf(s);
        float phi = fmaxf(nr * gw[(layer * 4 + l) * 32 + dd] + gb[(layer * 4 + l) * 32 + dd], 0.f);
        scale[dd * 4 + l] = phi / (nr + 1e-6f);
    }
    if (!last) {
        for (int o = t; o < 4096; o += 256) rwswP[o] = __float_as_uint(Wv_n[o]);
    } else {
        for (int o = t; o < 4096; o += 256) {
            rhs[o] = WvO[o];                                   // l = 0,1
            rwswP[o] = __float_as_uint(WvO[4096 + o]);         // l = 2,3
        }
    }
    __syncthreads();

    // S6: apply gate, write hnew
    for (int o = t; o < 512; o += 256) {
        int dd = o >> 4, m = o & 15;
        float v = hnS[m * 33 + dd] * scale[dd * 4 + lmap(m)];
        hnew[n * 512 + o] = v;
        hnS[m * 33 + dd] = v;
    }
    __syncthreads();

    if (!last) {
        for (int o = t; o < 512; o += 256) {
            int dd = o >> 4, m = o & 15, l = lmap(m);
            float s = 0.f;
            const uint32_t* wv = &rwswP[l * 1024 + dd];
            const float* hrow = &hnS[m * 33];
#pragma unroll
            for (int c = 0; c < 32; c++) s = fmaf(hrow[c], __uint_as_float(wv[c * 32]), s);
            vpre_n[n * 512 + o] = s;
        }
        if (t < 32) {
            float s = 0.f;
#pragma unroll
            for (int c = 0; c < 32; c++) s = fmaf(hnS[c * 33], Wq_n[c * 32 + t], s);
            red[t] = s;
        }
        __syncthreads();
        if (t < 32) {
            float s = 0.f;
#pragma unroll
            for (int j = 0; j < 32; j++) s = fmaf(Wk_n[t * 32 + j], red[j], s);
            wqk_n[n * 32 + t] = s;
        }
    } else {
        for (int o = t; o < 1024; o += 256) {
            int j = o >> 4, m = o & 15, l = lmap(m);
            float s = 0.f;
            const float* hrow = &hnS[m * 33];
            if (l < 2) {
                const float* wv = &rhs[l * 2048 + j];
#pragma unroll
                for (int c = 0; c < 32; c++) s = fmaf(hrow[c], wv[c * 64], s);
            } else {
                const uint32_t* wv = &rwswP[(l - 2) * 2048 + j];
#pragma unroll
                for (int c = 0; c < 32; c++) s = fmaf(hrow[c], __uint_as_float(wv[c * 64]), s);
            }
            U[n * 1024 + o] = s;
        }
        if (t < 64) {
            float s = 0.f;
#pragma unroll
            for (int c = 0; c < 32; c++) s = fmaf(hnS[c * 33], WqO[c * 64 + t], s);
            red[t] = s;
        }
        __syncthreads();
        if (t < 32) {
            float s = 0.f;
#pragma unroll
            for (int j = 0; j < 64; j++) s = fmaf(WkO[t * 64 + j], red[j], s);
            wq2[n * 32 + t] = s;
        }
    }
}

// Output-stage edge kernel + fused out_post (hout). 3 blocks/CU.
__global__ __launch_bounds__(256, 3) void k_out_edge(
    const float* __restrict__ x, const float* __restrict__ h,
    const float* __restrict__ w1o, const float* __restrict__ b1o,
    const float* __restrict__ wq2, const float* __restrict__ roW,
    const float* __restrict__ U, const float* __restrict__ WoO,
    const float* __restrict__ WskipO, float* __restrict__ hout)
{
    __shared__ uint32_t rosP[4096];               // fp16 pairs of roW c-neighbors
    __shared__ __align__(16) float rhs[128 * 36];
    __shared__ __align__(16) float yss[128 * 17];
    __shared__ float xs[384];
    __shared__ float w1s[512];
    __shared__ float b1s[32];
    __shared__ float wq2s[32];
    __shared__ float alphas[128];
    __shared__ float red[256];
    __shared__ float agg64s[64];
    __shared__ float sh_inv;

    int n = blockIdx.x, t = threadIdx.x;
    int g = n >> 7, b = n & 127;
    int gbase = g << 7;

    for (int o = t; o < 384; o += 256) xs[o] = x[gbase * 3 + o];
    for (int o = t; o < 512; o += 256) w1s[o] = w1o[o];
    if (t < 32) { b1s[t] = b1o[t]; wq2s[t] = wq2[n * 32 + t]; }
    for (int o = t; o < 4096; o += 256) {
        int j = o & 63, lc = o >> 6, cp = lc & 15, l = lc >> 4;
        rosP[o] = f2h2(roW[(l * 32 + 2 * cp) * 64 + j], roW[(l * 32 + 2 * cp + 1) * 64 + j]);
    }
    __syncthreads();

    // phase A split across 256 threads
    {
        int a = t & 127, dh = t >> 7;
        float rx = xs[b * 3 + 0] - xs[a * 3 + 0];
        float ry = xs[b * 3 + 1] - xs[a * 3 + 1];
        float rz = xs[b * 3 + 2] - xs[a * 3 + 2];
        float dd = sqrtf(rx * rx + ry * ry + rz * rz + 1e-12f);
        float inv = 1.f / dd;
        float ys[16];
        sph16(rx * inv, ry * inv, rz * inv, ys);
        if (dh == 0) {
#pragma unroll
            for (int m = 0; m < 16; m++) yss[a * 17 + m] = ys[m];
        }
        float rbf[16];
#pragma unroll
        for (int j = 0; j < 16; j++) {
            float dc = dd - (4.f / 15.f) * j;
            rbf[j] = __expf(-2.f * dc * dc);
        }
        float lpart = 0.f;
        int d0 = dh * 16;
        for (int d2 = 0; d2 < 16; d2++) {
            int d = d0 + d2;
            float s = b1s[d];
#pragma unroll
            for (int j = 0; j < 16; j++) s = fmaf(rbf[j], w1s[j * 32 + d], s);
            s = fmaxf(s, 0.f);
            rhs[a * 36 + d] = s;
            lpart = fmaf(s, wq2s[d], lpart);
        }
        red[t] = lpart;
    }
    __syncthreads();
    if (t < 128) alphas[t] = (red[t] + red[t + 128]) * 0.125f; // 1/sqrt(64)
    __syncthreads();

    red[t] = (t < 128 && t != b) ? alphas[t] : -1e30f;
    __syncthreads();
    for (int s2 = 128; s2 > 0; s2 >>= 1) { if (t < s2) red[t] = fmaxf(red[t], red[t + s2]); __syncthreads(); }
    float mx = red[0];
    __syncthreads();
    float e = (t < 128 && t != b) ? __expf(alphas[t] - mx) : 0.f;
    red[t] = e;
    __syncthreads();
    for (int s2 = 128; s2 > 0; s2 >>= 1) { if (t < s2) red[t] += red[t + s2]; __syncthreads(); }
    if (t == 0) sh_inv = 1.f / red[0];
    if (t < 128) alphas[t] = e;
    __syncthreads();

    int grp = t >> 6, j = t & 63;
    float accO = 0.f;
    for (int chunk = 0; chunk < 4; chunk++) {
        int a0 = grp * 32 + chunk * 8;
        float RO[8][4];
#pragma unroll
        for (int aa = 0; aa < 8; aa++)
#pragma unroll
            for (int l = 0; l < 4; l++) RO[aa][l] = 0.f;

#pragma unroll 2
        for (int cq = 0; cq < 8; cq++) {
            float4 rh4[8];
#pragma unroll
            for (int aa = 0; aa < 8; aa++)
                rh4[aa] = *reinterpret_cast<const float4*>(&rhs[(a0 + aa) * 36 + cq * 4]);
#pragma unroll
            for (int l = 0; l < 4; l++) {
#pragma unroll
                for (int ch = 0; ch < 2; ch++) {
                    float2 w2 = h2f2(rosP[(l * 16 + cq * 2 + ch) * 64 + j]);
#pragma unroll
                    for (int aa = 0; aa < 8; aa++) {
                        RO[aa][l] = fmaf(f4get(rh4[aa], 2 * ch), w2.x, RO[aa][l]);
                        RO[aa][l] = fmaf(f4get(rh4[aa], 2 * ch + 1), w2.y, RO[aa][l]);
                    }
                }
            }
        }

        float4 A0, A1, A2, A3, B0, B1, B2, B3;
        {
            const float4* p4 = reinterpret_cast<const float4*>(U + (gbase + a0) * 1024 + j * 16);
            A0 = p4[0]; A1 = p4[1]; A2 = p4[2]; A3 = p4[3];
            const float4* q4 = reinterpret_cast<const float4*>(U + (gbase + a0 + 1) * 1024 + j * 16);
            B0 = q4[0]; B1 = q4[1]; B2 = q4[2]; B3 = q4[3];
        }
#define PROC_O(aa, u0, u1, u2, u3) { \
        int a_ = a0 + (aa); \
        float w_ = alphas[a_]; \
        if (w_ != 0.f) { \
            const float* ysa = &yss[a_ * 17]; \
            float cv0 = ysa[0] * (u0).x; \
            float cv1 = fmaf(ysa[1], (u0).y, fmaf(ysa[2], (u0).z, ysa[3] * (u0).w)); \
            float cv2 = fmaf(ysa[4], (u1).x, fmaf(ysa[5], (u1).y, fmaf(ysa[6], (u1).z, fmaf(ysa[7], (u1).w, ysa[8] * (u2).x)))); \
            float cv3 = fmaf(ysa[9], (u2).y, fmaf(ysa[10], (u2).z, fmaf(ysa[11], (u2).w, \
                        fmaf(ysa[12], (u3).x, fmaf(ysa[13], (u3).y, fmaf(ysa[14], (u3).z, ysa[15] * (u3).w)))))); \
            float s_ = fmaf(cv0, RO[aa][0], fmaf(cv1, RO[aa][1], fmaf(cv2, RO[aa][2], cv3 * RO[aa][3]))); \
            accO = fmaf(w_, s_, accO); \
        } }
#pragma unroll
        for (int ap = 0; ap < 4; ap++) {
            int aa = ap * 2;
            {
                float4 u0 = A0, u1 = A1, u2 = A2, u3 = A3;
                if (ap < 3) {
                    const float4* p4 = reinterpret_cast<const float4*>(U + (gbase + a0 + aa + 2) * 1024 + j * 16);
                    A0 = p4[0]; A1 = p4[1]; A2 = p4[2]; A3 = p4[3];
                }
                PROC_O(aa, u0, u1, u2, u3)
            }
            {
                float4 u0 = B0, u1 = B1, u2 = B2, u3 = B3;
                if (ap < 3) {
                    const float4* p4 = reinterpret_cast<const float4*>(U + (gbase + a0 + aa + 3) * 1024 + j * 16);
                    B0 = p4[0]; B1 = p4[1]; B2 = p4[2]; B3 = p4[3];
                }
                PROC_O(aa + 1, u0, u1, u2, u3)
            }
        }
#undef PROC_O
    }
    red[t] = accO;
    __syncthreads();
    if (t < 64) agg64s[t] = (red[t] + red[64 + t] + red[128 + t] + red[192 + t]) * sh_inv;
    __syncthreads();

    if (t < 64) {
        float s = 0.f;
#pragma unroll
        for (int c = 0; c < 64; c++) s = fmaf(agg64s[c], WoO[c * 64 + t], s);
        const float* hr = &h[n * 512];
#pragma unroll
        for (int c = 0; c < 32; c++) s = fmaf(hr[c * 16], WskipO[c * 64 + t], s);
        hout[n * 64 + t] = s;
    }
}

__global__ __launch_bounds__(64) void k_final(
    const float* __restrict__ hout, const float* __restrict__ Whid,
    const float* __restrict__ bhid, const float* __restrict__ Wout,
    const float* __restrict__ bout, float* __restrict__ out)
{
    __shared__ float pooled[64], hid[64];
    int g = blockIdx.x, t = threadIdx.x;
    float s = 0.f;
    for (int p = 0; p < 128; p++) s += hout[(g * 128 + p) * 64 + t];
    pooled[t] = s * (1.f / 128.f);
    __syncthreads();
    float hv = bhid[t];
#pragma unroll
    for (int c = 0; c < 64; c++) hv = fmaf(pooled[c], Whid[c * 64 + t], hv);
    hid[t] = fmaxf(hv, 0.f);
    __syncthreads();
    if (t < 15) {
        float o = bout[t];
#pragma unroll
        for (int c = 0; c < 64; c++) o = fmaf(hid[c], Wout[c * 15 + t], o);
        out[g * 15 + t] = o;
    }
}

extern "C" void kernel_launch(void* const* d_in, const int* in_sizes, int n_in,
                              void* d_out, int out_size, void* d_ws, size_t ws_size,
                              hipStream_t stream) {
    const float* x      = (const float*)d_in[0];
    const float* w1     = (const float*)d_in[1];
    const float* b1     = (const float*)d_in[2];
    const float* rW     = (const float*)d_in[3];
    const float* sW     = (const float*)d_in[4];
    const float* Wv     = (const float*)d_in[5];
    const float* Wq     = (const float*)d_in[6];
    const float* Wk     = (const float*)d_in[7];
    const float* Wo     = (const float*)d_in[8];
    const float* Wskip  = (const float*)d_in[9];
    const float* gw     = (const float*)d_in[10];
    const float* gb     = (const float*)d_in[11];
    const float* w1o    = (const float*)d_in[12];
    const float* b1o    = (const float*)d_in[13];
    const float* roW    = (const float*)d_in[14];
    const float* WvO    = (const float*)d_in[15];
    const float* WqO    = (const float*)d_in[16];
    const float* WkO    = (const float*)d_in[17];
    const float* WoO    = (const float*)d_in[18];
    const float* WskipO = (const float*)d_in[19];
    const float* Whid   = (const float*)d_in[20];
    const float* bhid   = (const float*)d_in[21];
    const float* Wout   = (const float*)d_in[22];
    const float* bout   = (const float*)d_in[23];
    float* out = (float*)d_out;

    float* ws = (float*)d_ws;
    float* h0    = ws;
    float* h1    = h0 + NNODE * 512;
    float* vA    = h1 + NNODE * 512;
    float* wqkA  = vA + NNODE * 512;
    float* vB    = wqkA + NNODE * 32;
    float* wqkB  = vB + NNODE * 512;
    float* wq2   = wqkB + NNODE * 32;
    float* U     = wq2 + NNODE * 32;
    float* hout  = U + NNODE * 1024;

    hipMemsetAsync(h0, 0, NNODE * 512 * sizeof(float), stream);
    hipMemsetAsync(vA, 0, (NNODE * 512 + NNODE * 32) * sizeof(float), stream);

    for (int i = 0; i < 4; i++) {
        const float* hc  = (i & 1) ? h1 : h0;
        float*       hn  = (i & 1) ? h0 : h1;
        const float* vin  = (i & 1) ? vB : vA;
        const float* qin  = (i & 1) ? wqkB : wqkA;
        float*       vout = (i & 1) ? vA : vB;
        float*       qout = (i & 1) ? wqkA : wqkB;
        int last = (i == 3);
        k_layer<<<NNODE, 256, 0, stream>>>(
            x, hc, vin, qin, w1, b1, rW, sW, Wskip, Wo, gw, gb,
            Wv + (last ? 0 : (i + 1) * 4096),
            Wq + (last ? 0 : (i + 1) * 1024),
            Wk + (last ? 0 : (i + 1) * 1024),
            WvO, WqO, WkO,
            hn, vout, qout, wq2, U, i, last);
    }
    k_out_edge<<<NNODE, 256, 0, stream>>>(x, h0, w1o, b1o, wq2, roW, U, WoO, WskipO, hout);
    k_final<<<NGRAPH, 64, 0, stream>>>(hout, Whid, bhid, Wout, bout, out);
}